// Round 1
// 443.077 us; speedup vs baseline: 1.0768x; 1.0768x over previous
//
#include <hip/hip_runtime.h>
#include <math.h>

#define N_USERS 8192
#define N_ITEMS 4096
#define BATCH   8192
#define NTILE_I (N_ITEMS / 64)   // 64 item tiles per user stripe

// ---------------------------------------------------------------------------
// K_A: fused transpose + per-row partial sums.
//   AT[j][u] = (uint8)R[u][j]            (exact: R in {0..5})
//   psum[bx][u] = sum of R[u][ colBase .. colBase+63 ]
//   pcnt[bx][u] = nonzero count of same
// grid (NTILE_I, N_USERS/64), block (16,16).
// ---------------------------------------------------------------------------
__global__ __launch_bounds__(256) void k_trans(const float* __restrict__ R,
                                               unsigned char* __restrict__ AT,
                                               float* __restrict__ psum,
                                               float* __restrict__ pcnt) {
    __shared__ float lds[64][65];
    const int colBase = blockIdx.x * 64;   // item dim
    const int rowBase = blockIdx.y * 64;   // user dim
    const int tx = threadIdx.x, ty = threadIdx.y;
    const int x4 = tx * 4;

    float s[4], c[4];
    #pragma unroll
    for (int k = 0; k < 4; ++k) {
        const int y = ty + 16 * k;
        float4 v = *(const float4*)(R + (size_t)(rowBase + y) * N_ITEMS + colBase + x4);
        lds[y][x4 + 0] = v.x;
        lds[y][x4 + 1] = v.y;
        lds[y][x4 + 2] = v.z;
        lds[y][x4 + 3] = v.w;
        s[k] = v.x + v.y + v.z + v.w;
        c[k] = (v.x != 0.f) + (v.y != 0.f) + (v.z != 0.f) + (v.w != 0.f);
    }
    // reduce the 16 tx-lanes of each (ty,k) row group (lane = tx + 16*ty)
    #pragma unroll
    for (int k = 0; k < 4; ++k) {
        #pragma unroll
        for (int off = 8; off; off >>= 1) {
            s[k] += __shfl_down(s[k], off, 16);
            c[k] += __shfl_down(c[k], off, 16);
        }
    }
    if (tx == 0) {
        #pragma unroll
        for (int k = 0; k < 4; ++k) {
            const int u = rowBase + ty + 16 * k;
            psum[(size_t)blockIdx.x * N_USERS + u] = s[k];
            pcnt[(size_t)blockIdx.x * N_USERS + u] = c[k];
        }
    }
    __syncthreads();

    // store phase: 64 item-rows x 4 uchar16-chunks = 256 stores, 1 per thread
    const int tid = ty * 16 + tx;
    const int il = tid >> 2;              // local item row 0..63
    const int ch = tid & 3;               // user chunk (16 users)
    union { unsigned char b[16]; int4 v; } w;
    #pragma unroll
    for (int e = 0; e < 16; ++e) {
        w.b[e] = (unsigned char)(int)lds[ch * 16 + e][il];
    }
    *(int4*)(AT + (size_t)(colBase + il) * N_USERS + rowBase + ch * 16) = w.v;
}

// ---------------------------------------------------------------------------
// K_fin: ub[u] = cnt>0 ? sum/max(cnt,1) : 0   (reduce 64 tile-partials)
// 4-way segment split per user for 4x the wave parallelism of the old
// version (which ran only 128 waves on 256 CUs and was latency-bound).
// grid N_USERS/64 = 128 blocks x 256 thr.
// ---------------------------------------------------------------------------
__global__ __launch_bounds__(256) void k_fin(const float* __restrict__ psum,
                                             const float* __restrict__ pcnt,
                                             float* __restrict__ ub) {
    __shared__ float ss[4][64], sc[4][64];
    const int ul  = threadIdx.x & 63;
    const int seg = threadIdx.x >> 6;     // 0..3: which 16-tile segment
    const int u = blockIdx.x * 64 + ul;
    float s = 0.f, c = 0.f;
    #pragma unroll
    for (int k = 0; k < 16; ++k) {
        const int t = seg * 16 + k;
        s += psum[(size_t)t * N_USERS + u];
        c += pcnt[(size_t)t * N_USERS + u];
    }
    ss[seg][ul] = s;
    sc[seg][ul] = c;
    __syncthreads();
    if (seg == 0) {
        s = ss[0][ul] + ss[1][ul] + ss[2][ul] + ss[3][ul];
        c = sc[0][ul] + sc[1][ul] + sc[2][ul] + sc[3][ul];
        ub[u] = (c > 0.f) ? s / fmaxf(c, 1.f) : 0.f;
    }
}

// ---------------------------------------------------------------------------
// K_B: one WAVE per batch element, 8 waves (512 thr) per block.
//   out[b] = sigmoid( dot(S[user[b]], (float)AT[item[b]] - ub) + biases ) * 5
// ub is staged into 32 KiB LDS once per block: the old version re-read the
// 32 KiB ub array from global per wave (2 of 5 VMEM instrs in the hot loop,
// L1-thrashed by streaming S/AT). Now 3 VMEM + 2 ds_read_b128 per iter.
// Grid BATCH/8 x 512thr. LDS 32KiB -> 3-4 blocks/CU (24-32 waves).
// ---------------------------------------------------------------------------
__global__ __launch_bounds__(512, 6) void k_main(const float* __restrict__ S,
                                                 const unsigned char* __restrict__ AT,
                                                 const float* __restrict__ ub,
                                                 const int* __restrict__ user,
                                                 const int* __restrict__ item,
                                                 const float* __restrict__ ubias,
                                                 const float* __restrict__ ibias,
                                                 const float* __restrict__ gbias,
                                                 float* __restrict__ out) {
    __shared__ float4 ubs[N_USERS / 4];   // 32 KiB
    #pragma unroll
    for (int t = 0; t < 4; ++t) {
        ubs[t * 512 + threadIdx.x] = ((const float4*)ub)[t * 512 + threadIdx.x];
    }
    __syncthreads();

    const int wave = threadIdx.x >> 6;
    const int lane = threadIdx.x & 63;
    const int b = blockIdx.x * 8 + wave;
    const int su = user[b];
    const int j  = item[b];
    const float4* srow = (const float4*)(S + (size_t)su * N_USERS);
    const uint2*  arow = (const uint2*)(AT + (size_t)j * N_USERS);

    float acc = 0.f;
    #pragma unroll 4
    for (int i = 0; i < 16; ++i) {
        const int idx = i * 64 + lane;       // unit = 8 users
        uint2  a  = arow[idx];
        float4 s0 = srow[2 * idx + 0];
        float4 s1 = srow[2 * idx + 1];
        float4 u0 = ubs[2 * idx + 0];
        float4 u1 = ubs[2 * idx + 1];
        acc += s0.x * ((float)( a.x        & 0xffu) - u0.x);
        acc += s0.y * ((float)((a.x >>  8) & 0xffu) - u0.y);
        acc += s0.z * ((float)((a.x >> 16) & 0xffu) - u0.z);
        acc += s0.w * ((float)( a.x >> 24         ) - u0.w);
        acc += s1.x * ((float)( a.y        & 0xffu) - u1.x);
        acc += s1.y * ((float)((a.y >>  8) & 0xffu) - u1.y);
        acc += s1.z * ((float)((a.y >> 16) & 0xffu) - u1.z);
        acc += s1.w * ((float)( a.y >> 24         ) - u1.w);
    }
    #pragma unroll
    for (int off = 32; off; off >>= 1) acc += __shfl_down(acc, off);

    if (lane == 0) {
        float score = acc + ubias[su] + ibias[j] + gbias[0];
        out[b] = 5.f / (1.f + expf(-score));
    }
}

// ---------------------------------------------------------------------------
// Fallback path (ws too small): original 3-pass f32 scheme.
// ---------------------------------------------------------------------------
__global__ __launch_bounds__(256) void k_ubfix(const float* __restrict__ R,
                                               float* __restrict__ ub) {
    const int wave = threadIdx.x >> 6;
    const int lane = threadIdx.x & 63;
    const int u = blockIdx.x * 4 + wave;
    const float4* row4 = (const float4*)(R + (size_t)u * N_ITEMS);
    float s = 0.f, c = 0.f;
    #pragma unroll
    for (int i = 0; i < 16; ++i) {
        float4 v = row4[i * 64 + lane];
        s += v.x + v.y + v.z + v.w;
        c += (v.x != 0.f) + (v.y != 0.f) + (v.z != 0.f) + (v.w != 0.f);
    }
    #pragma unroll
    for (int off = 32; off; off >>= 1) {
        s += __shfl_down(s, off);
        c += __shfl_down(c, off);
    }
    if (lane == 0)
        ub[u] = (c > 0.f) ? s / fmaxf(c, 1.f) : 0.f;
}

__global__ __launch_bounds__(256) void k_direct(const float* __restrict__ S,
                                                const float* __restrict__ R,
                                                const float* __restrict__ ub,
                                                const int* __restrict__ user,
                                                const int* __restrict__ item,
                                                const float* __restrict__ ubias,
                                                const float* __restrict__ ibias,
                                                const float* __restrict__ gbias,
                                                float* __restrict__ out) {
    const int b = blockIdx.x;
    const int su = user[b];
    const int j  = item[b];
    const float* srow = S + (size_t)su * N_USERS;
    float acc = 0.f;
    for (int u = threadIdx.x; u < N_USERS; u += 256) {
        acc += srow[u] * (R[(size_t)u * N_ITEMS + j] - ub[u]);
    }
    for (int off = 32; off; off >>= 1) acc += __shfl_down(acc, off);
    __shared__ float sa[4];
    const int lane = threadIdx.x & 63, w = threadIdx.x >> 6;
    if (lane == 0) sa[w] = acc;
    __syncthreads();
    if (threadIdx.x == 0) {
        float score = sa[0] + sa[1] + sa[2] + sa[3]
                    + ubias[su] + ibias[j] + gbias[0];
        out[b] = 5.f / (1.f + expf(-score));
    }
}

extern "C" void kernel_launch(void* const* d_in, const int* in_sizes, int n_in,
                              void* d_out, int out_size, void* d_ws, size_t ws_size,
                              hipStream_t stream) {
    const int*   user  = (const int*)d_in[0];
    const int*   item  = (const int*)d_in[1];
    const float* R     = (const float*)d_in[2];   // [N_USERS][N_ITEMS] f32
    const float* S     = (const float*)d_in[3];   // [N_USERS][N_USERS] f32
    const float* ubias = (const float*)d_in[4];
    const float* ibias = (const float*)d_in[5];
    const float* gbias = (const float*)d_in[6];
    float* out = (float*)d_out;

    // ws layout:
    //   [0, 32KB)            ub[N_USERS] f32
    //   [64KB, 64KB+2MB)     psum[NTILE_I][N_USERS] f32
    //   [64KB+2MB, +2MB)     pcnt[NTILE_I][N_USERS] f32
    //   [8MB, 8MB+33.5MB)    AT[N_ITEMS][N_USERS] uint8
    float* ub   = (float*)d_ws;
    float* psum = (float*)((char*)d_ws + (64u << 10));
    float* pcnt = (float*)((char*)d_ws + (64u << 10) + ((size_t)NTILE_I * N_USERS * 4));
    unsigned char* AT = (unsigned char*)((char*)d_ws + (8u << 20));
    const size_t need = (8u << 20) + (size_t)N_ITEMS * N_USERS;

    if (ws_size >= need) {
        dim3 tgrid(NTILE_I, N_USERS / 64);
        dim3 tblk(16, 16);
        k_trans<<<tgrid, tblk, 0, stream>>>(R, AT, psum, pcnt);
        k_fin<<<N_USERS / 64, 256, 0, stream>>>(psum, pcnt, ub);
        k_main<<<BATCH / 8, 512, 0, stream>>>(S, AT, ub, user, item, ubias, ibias, gbias, out);
    } else {
        k_ubfix<<<N_USERS / 4, 256, 0, stream>>>(R, ub);
        k_direct<<<BATCH, 256, 0, stream>>>(S, R, ub, user, item, ubias, ibias, gbias, out);
    }
}